// Round 5
// baseline (408.675 us; speedup 1.0000x reference)
//
#include <hip/hip_runtime.h>

// WL_DiffNet bf16-MFMA, round 5: split gather (no-LDS, high-occupancy) from
// GEMM; fold gemmA for depths>=1 into megaGEMM (F' tile reused from LDS for
// G' = F'@W2a); pk indices precomputed once.
//   per depth: Nsg = gather(G,Hb2,pk);  [F'|G'] = megaGEMM(F, Nsg)
// Math identical to round 4 (absmax expected 0.0625).

#define BB 64
#define NN 512
#define MAXNB 10
#define HH 256
#define ROWS (BB*NN)   // 32768

typedef __attribute__((ext_vector_type(8))) short bf16x8;
typedef __attribute__((ext_vector_type(4))) float f32x4;
typedef unsigned short u16;
typedef unsigned int u32;

__device__ __forceinline__ u16 f2b(float f) {   // rne f32->bf16
    union { float f; u32 u; } v; v.f = f;
    u32 r = v.u + 0x7FFF + ((v.u >> 16) & 1);
    return (u16)(r >> 16);
}
__device__ __forceinline__ float b2f(u32 u) {   // low 16 bits -> f32
    union { u32 u; float f; } v; v.u = u << 16; return v.f;
}
__device__ __forceinline__ float b2fh(u32 u) {  // high 16 bits -> f32
    union { u32 u; float f; } v; v.u = u & 0xffff0000u; return v.f;
}

// XCD-bijective swizzle (nwg % 8 == 0): XCD x owns contiguous tile chunk.
__device__ __forceinline__ int xcd_swz(int bid, int nwg) {
    return (bid & 7) * (nwg >> 3) + (bid >> 3);
}

// ---- one-time prep -------------------------------------------------------

__global__ __launch_bounds__(256) void castk(const float* __restrict__ in,
                                             u16* __restrict__ out) {
    int i = blockIdx.x * 256 + threadIdx.x;
    float4 v = ((const float4*)in)[i];
    u32 a = f2b(v.x) | ((u32)f2b(v.y) << 16);
    u32 b = f2b(v.z) | ((u32)f2b(v.w) << 16);
    ((uint2*)out)[i] = make_uint2(a, b);
}

__global__ __launch_bounds__(256) void twk(const float* __restrict__ W,
                                           u16* __restrict__ WT, int K) {
    int k = blockIdx.x, n = threadIdx.x;
    WT[(size_t)n * K + k] = f2b(W[(size_t)k * HH + n]);
}

__global__ __launch_bounds__(256) void hb2_kernel(const float* __restrict__ bond,
                                                  const float* __restrict__ W2,
                                                  const float* __restrict__ b2,
                                                  u16* __restrict__ Hb2) {
    int c = threadIdx.x;
    int r0 = blockIdx.x * 8;
    float w[5];
#pragma unroll
    for (int f = 0; f < 5; ++f) w[f] = W2[(size_t)(HH + f) * HH + c];
    float bb = b2[c];
    for (int r = r0; r < r0 + 8; ++r) {
        float s = bb;
#pragma unroll
        for (int f = 0; f < 5; ++f) s += bond[r * 5 + f] * w[f];
        Hb2[(size_t)r * HH + c] = f2b(s);
    }
}

// pk[t] = an | bn<<9 | valid<<18  (loop-invariant, computed once)
__global__ __launch_bounds__(256) void pkk(const int* __restrict__ agr,
                                           const int* __restrict__ bgr,
                                           const int* __restrict__ nnb,
                                           int* __restrict__ pk) {
    int t = blockIdx.x * 256 + threadIdx.x;   // < 327680
    int r = t / 10, k = t - r * 10;
    int an = agr[t * 2 + 1];
    int bn = bgr[t * 2 + 1];
    int valid = (k < nnb[r]) ? 1 : 0;
    pk[t] = an | (bn << 9) | (valid << 18);
}

// ---- gemmA: G0[32r x 256] = Fbf @ W2aT^T (initial depth only) ------------

__global__ __launch_bounds__(256) void gemmA_mfma(const u16* __restrict__ Fbf,
                                                  const u16* __restrict__ W2aT,
                                                  u16* __restrict__ G) {
    __shared__ u16 As[32 * 256];   // 16KB, swizzled 16B slots
    int tid = threadIdx.x;
    int base = xcd_swz(blockIdx.x, gridDim.x) * 32;
    const uint4* src = (const uint4*)(Fbf + (size_t)base * 256);
#pragma unroll
    for (int i = 0; i < 4; ++i) {
        int ci = tid + i * 256;
        int row = ci >> 5, s = ci & 31;
        ((uint4*)As)[row * 32 + (s ^ (row & 7))] = src[ci];
    }
    __syncthreads();

    int lane = tid & 63, wid = tid >> 6;
    int r0 = (wid & 1) * 16, c0 = (wid >> 1) * 128;
    int m = lane & 15, g = lane >> 4;
    int arow = r0 + m;
    f32x4 acc[8];
#pragma unroll
    for (int j = 0; j < 8; ++j) acc[j] = (f32x4){0.f, 0.f, 0.f, 0.f};

    for (int ks = 0; ks < 8; ++ks) {
        bf16x8 a = *(const bf16x8*)(As + arow * 256 + (((ks * 4 + g) ^ (arow & 7)) * 8));
#pragma unroll
        for (int j = 0; j < 8; ++j) {
            int n = c0 + j * 16 + m;
            bf16x8 b = *(const bf16x8*)(W2aT + (size_t)n * 256 + ks * 32 + g * 8);
            acc[j] = __builtin_amdgcn_mfma_f32_16x16x32_bf16(a, b, acc[j], 0, 0, 0);
        }
    }
#pragma unroll
    for (int j = 0; j < 8; ++j) {
        int col = c0 + j * 16 + m;
#pragma unroll
        for (int rr = 0; rr < 4; ++rr)
            G[(size_t)(base + r0 + g * 4 + rr) * 256 + col] = f2b(acc[j][rr]);
    }
}

// ---- gather: Nsg[r] = sum_k relu(G[an]+Hb2[bn]) (no LDS, no barriers) ----

__global__ __launch_bounds__(256) void gather_k(const u16* __restrict__ G,
                                                const u16* __restrict__ Hb2,
                                                const int* __restrict__ pk,
                                                u16* __restrict__ Nsg) {
    int tid = threadIdx.x;
    int base = xcd_swz(blockIdx.x, gridDim.x) * 32;
    int brow = base & ~511;        // batch row base
    int q = tid >> 6;              // rows [q*8, q*8+8)
    int lane = tid & 63;           // uint2 slot = 4 bf16 cols
    const uint2* Gb = (const uint2*)(G + (size_t)brow * 256) + lane;
    const uint2* Hb = (const uint2*)(Hb2 + (size_t)brow * 256) + lane;
    const int* pkb = pk + (size_t)base * 10;

    for (int r = q * 8; r < q * 8 + 8; ++r) {
        float s0 = 0.f, s1 = 0.f, s2 = 0.f, s3 = 0.f;
#pragma unroll
        for (int k = 0; k < MAXNB; ++k) {
            int p = pkb[r * 10 + k];
            uint2 ga = Gb[(size_t)(p & 511) * 64];
            uint2 hb = Hb[(size_t)((p >> 9) & 511) * 64];
            float v0 = fmaxf(b2f(ga.x) + b2f(hb.x), 0.f);
            float v1 = fmaxf(b2fh(ga.x) + b2fh(hb.x), 0.f);
            float v2 = fmaxf(b2f(ga.y) + b2f(hb.y), 0.f);
            float v3 = fmaxf(b2fh(ga.y) + b2fh(hb.y), 0.f);
            bool valid = (p & (1 << 18)) != 0;
            s0 += valid ? v0 : 0.f;
            s1 += valid ? v1 : 0.f;
            s2 += valid ? v2 : 0.f;
            s3 += valid ? v3 : 0.f;
        }
        u32 lo = f2b(s0) | ((u32)f2b(s1) << 16);
        u32 hi = f2b(s2) | ((u32)f2b(s3) << 16);
        ((uint2*)(Nsg + (size_t)(base + r) * 256))[lane] = make_uint2(lo, hi);
    }
}

// ---- megaGEMM: F' = relu([F|N]@W1+b1); G' = F'@W2a (from LDS F' tile) ----

__global__ __launch_bounds__(256) void mega_mfma(const u16* __restrict__ Fbf,
                                                 const u16* __restrict__ Nsg,
                                                 const u16* __restrict__ W1T,
                                                 const float* __restrict__ b1,
                                                 const u16* __restrict__ W2aT,
                                                 u16* __restrict__ Fout,
                                                 u16* __restrict__ Gout) {
    __shared__ u16 Fs[32 * 256];   // 16KB, swizzled; later reused for F' tile
    __shared__ u16 Ns[32 * 256];   // 16KB, swizzled
    int tid = threadIdx.x;
    int base = xcd_swz(blockIdx.x, gridDim.x) * 32;

    const uint4* srcF = (const uint4*)(Fbf + (size_t)base * 256);
    const uint4* srcN = (const uint4*)(Nsg + (size_t)base * 256);
#pragma unroll
    for (int i = 0; i < 4; ++i) {
        int ci = tid + i * 256;
        int row = ci >> 5, s = ci & 31;
        ((uint4*)Fs)[row * 32 + (s ^ (row & 7))] = srcF[ci];
        ((uint4*)Ns)[row * 32 + (s ^ (row & 7))] = srcN[ci];
    }
    __syncthreads();

    int lane = tid & 63, wid = tid >> 6;
    int r0 = (wid & 1) * 16, c0 = (wid >> 1) * 128;
    int m = lane & 15, g = lane >> 4;
    int arow = r0 + m;
    f32x4 acc[8];
#pragma unroll
    for (int j = 0; j < 8; ++j) acc[j] = (f32x4){0.f, 0.f, 0.f, 0.f};

    // K = 512: [Fs | Ns] @ W1
    for (int ks = 0; ks < 8; ++ks) {
        bf16x8 a = *(const bf16x8*)(Fs + arow * 256 + (((ks * 4 + g) ^ (arow & 7)) * 8));
#pragma unroll
        for (int j = 0; j < 8; ++j) {
            int n = c0 + j * 16 + m;
            bf16x8 b = *(const bf16x8*)(W1T + (size_t)n * 512 + ks * 32 + g * 8);
            acc[j] = __builtin_amdgcn_mfma_f32_16x16x32_bf16(a, b, acc[j], 0, 0, 0);
        }
    }
    for (int ks = 0; ks < 8; ++ks) {
        bf16x8 a = *(const bf16x8*)(Ns + arow * 256 + (((ks * 4 + g) ^ (arow & 7)) * 8));
#pragma unroll
        for (int j = 0; j < 8; ++j) {
            int n = c0 + j * 16 + m;
            bf16x8 b = *(const bf16x8*)(W1T + (size_t)n * 512 + (ks + 8) * 32 + g * 8);
            acc[j] = __builtin_amdgcn_mfma_f32_16x16x32_bf16(a, b, acc[j], 0, 0, 0);
        }
    }

    // epilogue: F' = relu(acc + b1) -> global + LDS (reuse Fs)
    __syncthreads();   // all phase-1 LDS reads complete before overwrite
#pragma unroll
    for (int j = 0; j < 8; ++j) {
        int col = c0 + j * 16 + m;
        float bb = b1[col];
#pragma unroll
        for (int rr = 0; rr < 4; ++rr) {
            int rl = r0 + g * 4 + rr;
            u16 v = f2b(fmaxf(acc[j][rr] + bb, 0.f));
            Fout[(size_t)(base + rl) * 256 + col] = v;
            Fs[rl * 256 + (((col >> 3) ^ (rl & 7)) * 8) + (col & 7)] = v;
        }
    }

    if (Gout) {
        __syncthreads();
        f32x4 gacc[8];
#pragma unroll
        for (int j = 0; j < 8; ++j) gacc[j] = (f32x4){0.f, 0.f, 0.f, 0.f};
        for (int ks = 0; ks < 8; ++ks) {
            bf16x8 a = *(const bf16x8*)(Fs + arow * 256 + (((ks * 4 + g) ^ (arow & 7)) * 8));
#pragma unroll
            for (int j = 0; j < 8; ++j) {
                int n = c0 + j * 16 + m;
                bf16x8 b = *(const bf16x8*)(W2aT + (size_t)n * 256 + ks * 32 + g * 8);
                gacc[j] = __builtin_amdgcn_mfma_f32_16x16x32_bf16(a, b, gacc[j], 0, 0, 0);
            }
        }
#pragma unroll
        for (int j = 0; j < 8; ++j) {
            int col = c0 + j * 16 + m;
#pragma unroll
            for (int rr = 0; rr < 4; ++rr)
                Gout[(size_t)(base + r0 + g * 4 + rr) * 256 + col] = f2b(gacc[j][rr]);
        }
    }
}

// ---- final sum over atoms (deterministic) --------------------------------

__global__ __launch_bounds__(256) void sum_bf16(const u16* __restrict__ F,
                                                float* __restrict__ out) {
    __shared__ float red[4][256];
    int b = blockIdx.x, tid = threadIdx.x;
    int cg = tid & 63, rg = tid >> 6;
    float s0 = 0, s1 = 0, s2 = 0, s3 = 0;
    const u16* Fb = F + (size_t)(b * NN + rg * 128) * 256 + cg * 4;
    for (int n = 0; n < 128; ++n) {
        ushort4 v = *(const ushort4*)(Fb + (size_t)n * 256);
        s0 += b2f(v.x); s1 += b2f(v.y); s2 += b2f(v.z); s3 += b2f(v.w);
    }
    red[rg][cg * 4 + 0] = s0; red[rg][cg * 4 + 1] = s1;
    red[rg][cg * 4 + 2] = s2; red[rg][cg * 4 + 3] = s3;
    __syncthreads();
    if (rg == 0) {
#pragma unroll
        for (int j = 0; j < 4; ++j) {
            int cc = cg * 4 + j;
            out[b * 256 + cc] = (red[0][cc] + red[1][cc]) + (red[2][cc] + red[3][cc]);
        }
    }
}

extern "C" void kernel_launch(void* const* d_in, const int* in_sizes, int n_in,
                              void* d_out, int out_size, void* d_ws, size_t ws_size,
                              hipStream_t stream) {
    const float* input_bond    = (const float*)d_in[1];
    const int*   atom_graph    = (const int*)d_in[2];
    const int*   bond_graph    = (const int*)d_in[3];
    const int*   num_nbs       = (const int*)d_in[4];
    const float* atom_features = (const float*)d_in[5];
    const float* W2 = (const float*)d_in[6];
    const float* b2 = (const float*)d_in[7];
    const float* W1 = (const float*)d_in[8];
    const float* b1 = (const float*)d_in[9];
    float* out = (float*)d_out;

    char* w = (char*)d_ws;
    u16* f0   = (u16*)w;                                      // 16MB
    u16* f1   = (u16*)(w + ((size_t)16 << 20));               // 16MB
    u16* G    = (u16*)(w + ((size_t)32 << 20));               // 16MB
    u16* Hb2  = (u16*)(w + ((size_t)48 << 20));               // 16MB
    u16* Nsg  = (u16*)(w + ((size_t)64 << 20));               // 16MB
    u16* W2aT = (u16*)(w + ((size_t)80 << 20));               // 128KB
    u16* W1T  = (u16*)(w + ((size_t)80 << 20) + (256 << 10)); // 256KB
    int* pk   = (int*)(w + ((size_t)81 << 20));               // 1.25MB

    castk<<<ROWS * HH / 1024, 256, 0, stream>>>(atom_features, f0);
    twk<<<256, 256, 0, stream>>>(W2, W2aT, 256);
    twk<<<512, 256, 0, stream>>>(W1, W1T, 512);
    hb2_kernel<<<ROWS / 8, 256, 0, stream>>>(input_bond, W2, b2, Hb2);
    pkk<<<ROWS * MAXNB / 256, 256, 0, stream>>>(atom_graph, bond_graph, num_nbs, pk);

    gemmA_mfma<<<ROWS / 32, 256, 0, stream>>>(f0, W2aT, G);

    const u16* fin = f0;
    u16* fout = f1;
    for (int d = 0; d < 3; ++d) {
        gather_k<<<ROWS / 32, 256, 0, stream>>>(G, Hb2, pk, Nsg);
        mega_mfma<<<ROWS / 32, 256, 0, stream>>>(fin, Nsg, W1T, b1, W2aT,
                                                 fout, (d < 2) ? G : (u16*)nullptr);
        fin = fout;
        fout = (fout == f1) ? f0 : f1;
    }
    sum_bf16<<<BB, 256, 0, stream>>>(fin, out);
}

// Round 6
// 302.179 us; speedup vs baseline: 1.3524x; 1.3524x over previous
//
#include <hip/hip_runtime.h>

// WL_DiffNet bf16-MFMA, round 6: weight-amortized mega GEMM.
//   mega: M=64 rows/block, 8 waves, K-tiled(64) LDS-staged A/B with T14
//   register prefetch (issue next tile's loads before current compute).
//   Phase-1: F' = relu([F|N]@W1+b1) -> global + LDS(Fp, swizzled)
//   Phase-2: G' = F'@W2a (A-frags straight from Fp)      [skipped last depth]
//   Skip-mode (W1T==null): stage Fp from F, phase-2 only  [replaces gemmA]
// gather: 16 rows/block (grid 2048, 8 blocks/CU), no LDS, no barriers.

#define BB 64
#define NN 512
#define MAXNB 10
#define HH 256
#define ROWS (BB*NN)   // 32768
#define BM 64          // mega rows per block
#define GROWS 16       // gather rows per block

typedef __attribute__((ext_vector_type(8))) short bf16x8;
typedef __attribute__((ext_vector_type(4))) float f32x4;
typedef unsigned short u16;
typedef unsigned int u32;

__device__ __forceinline__ u16 f2b(float f) {   // rne f32->bf16
    union { float f; u32 u; } v; v.f = f;
    u32 r = v.u + 0x7FFF + ((v.u >> 16) & 1);
    return (u16)(r >> 16);
}
__device__ __forceinline__ float b2f(u32 u) {   // low 16 bits -> f32
    union { u32 u; float f; } v; v.u = u << 16; return v.f;
}
__device__ __forceinline__ float b2fh(u32 u) {  // high 16 bits -> f32
    union { u32 u; float f; } v; v.u = u & 0xffff0000u; return v.f;
}

// XCD-bijective swizzle (nwg % 8 == 0): XCD x owns contiguous tile chunk.
__device__ __forceinline__ int xcd_swz(int bid, int nwg) {
    return (bid & 7) * (nwg >> 3) + (bid >> 3);
}

// ---- one-time prep -------------------------------------------------------

__global__ __launch_bounds__(256) void castk(const float* __restrict__ in,
                                             u16* __restrict__ out) {
    int i = blockIdx.x * 256 + threadIdx.x;
    float4 v = ((const float4*)in)[i];
    u32 a = f2b(v.x) | ((u32)f2b(v.y) << 16);
    u32 b = f2b(v.z) | ((u32)f2b(v.w) << 16);
    ((uint2*)out)[i] = make_uint2(a, b);
}

__global__ __launch_bounds__(256) void twk(const float* __restrict__ W,
                                           u16* __restrict__ WT, int K) {
    int k = blockIdx.x, n = threadIdx.x;
    WT[(size_t)n * K + k] = f2b(W[(size_t)k * HH + n]);
}

__global__ __launch_bounds__(256) void hb2_kernel(const float* __restrict__ bond,
                                                  const float* __restrict__ W2,
                                                  const float* __restrict__ b2,
                                                  u16* __restrict__ Hb2) {
    int c = threadIdx.x;
    int r0 = blockIdx.x * 8;
    float w[5];
#pragma unroll
    for (int f = 0; f < 5; ++f) w[f] = W2[(size_t)(HH + f) * HH + c];
    float bb = b2[c];
    for (int r = r0; r < r0 + 8; ++r) {
        float s = bb;
#pragma unroll
        for (int f = 0; f < 5; ++f) s += bond[r * 5 + f] * w[f];
        Hb2[(size_t)r * HH + c] = f2b(s);
    }
}

// pk[t] = an | bn<<9 | valid<<18  (loop-invariant, computed once)
__global__ __launch_bounds__(256) void pkk(const int* __restrict__ agr,
                                           const int* __restrict__ bgr,
                                           const int* __restrict__ nnb,
                                           int* __restrict__ pk) {
    int t = blockIdx.x * 256 + threadIdx.x;   // < 327680
    int r = t / 10, k = t - r * 10;
    int an = agr[t * 2 + 1];
    int bn = bgr[t * 2 + 1];
    int valid = (k < nnb[r]) ? 1 : 0;
    pk[t] = an | (bn << 9) | (valid << 18);
}

// ---- gather: Nsg[r] = sum_k relu(G[an]+Hb2[bn]) --------------------------

__global__ __launch_bounds__(256) void gather_k(const u16* __restrict__ G,
                                                const u16* __restrict__ Hb2,
                                                const int* __restrict__ pk,
                                                u16* __restrict__ Nsg) {
    int tid = threadIdx.x;
    int base = xcd_swz(blockIdx.x, gridDim.x) * GROWS;
    int brow = base & ~511;        // batch row base (16 | 512)
    int q = tid >> 6;              // rows [q*4, q*4+4)
    int lane = tid & 63;           // uint2 slot = 4 bf16 cols
    const uint2* Gb = (const uint2*)(G + (size_t)brow * 256) + lane;
    const uint2* Hb = (const uint2*)(Hb2 + (size_t)brow * 256) + lane;
    const int* pkb = pk + (size_t)base * 10;

    for (int r = q * 4; r < q * 4 + 4; ++r) {
        float s0 = 0.f, s1 = 0.f, s2 = 0.f, s3 = 0.f;
#pragma unroll
        for (int k = 0; k < MAXNB; ++k) {
            int p = pkb[r * 10 + k];
            uint2 ga = Gb[(size_t)(p & 511) * 64];
            uint2 hb = Hb[(size_t)((p >> 9) & 511) * 64];
            float v0 = fmaxf(b2f(ga.x) + b2f(hb.x), 0.f);
            float v1 = fmaxf(b2fh(ga.x) + b2fh(hb.x), 0.f);
            float v2 = fmaxf(b2f(ga.y) + b2f(hb.y), 0.f);
            float v3 = fmaxf(b2fh(ga.y) + b2fh(hb.y), 0.f);
            bool valid = (p & (1 << 18)) != 0;
            s0 += valid ? v0 : 0.f;
            s1 += valid ? v1 : 0.f;
            s2 += valid ? v2 : 0.f;
            s3 += valid ? v3 : 0.f;
        }
        u32 lo = f2b(s0) | ((u32)f2b(s1) << 16);
        u32 hi = f2b(s2) | ((u32)f2b(s3) << 16);
        ((uint2*)(Nsg + (size_t)(base + r) * 256))[lane] = make_uint2(lo, hi);
    }
}

// ---- mega: F'=relu([F|N]@W1+b1) (+LDS), then G'=F'@W2a -------------------
// 512 thr, 8 waves (2 row x 4 col), M=64, N=256, K-tile 64.
// LDS: Fp[64][256] 32KB (As[64][64] 8KB aliased at its start during phase-1),
//      Bs[256][64] 32KB. All XOR-swizzled: 16B slot s -> s ^ (row&7).

__global__ __launch_bounds__(512, 2) void mega2(const u16* __restrict__ Fbf,
                                                const u16* __restrict__ Nsg,
                                                const u16* __restrict__ W1T,
                                                const float* __restrict__ b1,
                                                const u16* __restrict__ W2aT,
                                                u16* __restrict__ Fout,
                                                u16* __restrict__ Gout) {
    __shared__ u16 Fp[BM * 256];   // 32KB
    __shared__ u16 Bs[256 * 64];   // 32KB
    u16* As = Fp;                  // 8KB alias, dead before Fp is written

    int tid = threadIdx.x;
    int base = xcd_swz(blockIdx.x, gridDim.x) * BM;
    int lane = tid & 63, wid = tid >> 6;
    int wr = wid >> 2, wc = wid & 3;       // wave tile: rows wr*32+, cols wc*64+
    int m = lane & 15, g = lane >> 4;

    // staging coords
    int arow = tid >> 3, aslt = tid & 7;   // As: 1 uint4/thread

    if (W1T) {
        f32x4 acc[2][4];
#pragma unroll
        for (int mi = 0; mi < 2; ++mi)
#pragma unroll
            for (int j = 0; j < 4; ++j) acc[mi][j] = (f32x4){0.f, 0.f, 0.f, 0.f};

        // phase-1: K=512 over 8 k-tiles; A = F (kt<4) | N (kt>=4)
        uint4 pa, pb[4];
        {
            const u16* srcA = Fbf + (size_t)(base + arow) * 256 + aslt * 8;
            pa = *(const uint4*)srcA;
#pragma unroll
            for (int r = 0; r < 4; ++r) {
                int ci = tid + r * 512, n = ci >> 3, s = ci & 7;
                pb[r] = *(const uint4*)(W1T + (size_t)n * 512 + s * 8);
            }
        }
        for (int kt = 0; kt < 8; ++kt) {
            __syncthreads();
            ((uint4*)As)[arow * 8 + (aslt ^ (arow & 7))] = pa;
#pragma unroll
            for (int r = 0; r < 4; ++r) {
                int ci = tid + r * 512, n = ci >> 3, s = ci & 7;
                ((uint4*)Bs)[n * 8 + (s ^ (n & 7))] = pb[r];
            }
            if (kt < 7) {
                const u16* srcA = ((kt + 1 < 4) ? Fbf : Nsg) +
                                  (size_t)(base + arow) * 256 + ((kt + 1) & 3) * 64 + aslt * 8;
                pa = *(const uint4*)srcA;
#pragma unroll
                for (int r = 0; r < 4; ++r) {
                    int ci = tid + r * 512, n = ci >> 3, s = ci & 7;
                    pb[r] = *(const uint4*)(W1T + (size_t)n * 512 + (kt + 1) * 64 + s * 8);
                }
            }
            __syncthreads();
#pragma unroll
            for (int ks = 0; ks < 2; ++ks) {
                bf16x8 af[2], bf[4];
#pragma unroll
                for (int mi = 0; mi < 2; ++mi) {
                    int r = wr * 32 + mi * 16 + m;
                    af[mi] = *(const bf16x8*)(As + r * 64 + (((ks * 4 + g) ^ (r & 7)) * 8));
                }
#pragma unroll
                for (int j = 0; j < 4; ++j) {
                    int n = wc * 64 + j * 16 + m;
                    bf[j] = *(const bf16x8*)(Bs + n * 64 + (((ks * 4 + g) ^ (n & 7)) * 8));
                }
#pragma unroll
                for (int mi = 0; mi < 2; ++mi)
#pragma unroll
                    for (int j = 0; j < 4; ++j)
                        acc[mi][j] = __builtin_amdgcn_mfma_f32_16x16x32_bf16(
                            af[mi], bf[j], acc[mi][j], 0, 0, 0);
            }
        }
        __syncthreads();   // As (aliased by Fp) fully read before epilogue writes

        // epilogue: F' = relu(acc + b1) -> global (+ Fp for phase-2)
#pragma unroll
        for (int mi = 0; mi < 2; ++mi)
#pragma unroll
            for (int j = 0; j < 4; ++j) {
                int col = wc * 64 + j * 16 + m;
                float bb = b1[col];
#pragma unroll
                for (int rr = 0; rr < 4; ++rr) {
                    int r = wr * 32 + mi * 16 + g * 4 + rr;
                    u16 v = f2b(fmaxf(acc[mi][j][rr] + bb, 0.f));
                    Fout[(size_t)(base + r) * 256 + col] = v;
                    if (Gout)
                        Fp[r * 256 + ((col >> 3) ^ (r & 7)) * 8 + (col & 7)] = v;
                }
            }
    } else {
        // skip-mode: stage Fp directly from Fbf (phase-2 computes G0 = F@W2a)
        const uint4* srcF = (const uint4*)(Fbf + (size_t)base * 256);
#pragma unroll
        for (int i = 0; i < 4; ++i) {
            int ci = tid + i * 512, row = ci >> 5, s = ci & 31;
            ((uint4*)Fp)[row * 32 + (s ^ (row & 7))] = srcF[ci];
        }
    }

    if (!Gout) return;

    // phase-2: G' = Fp @ W2a, K=256 over 4 k-tiles
    f32x4 gacc[2][4];
#pragma unroll
    for (int mi = 0; mi < 2; ++mi)
#pragma unroll
        for (int j = 0; j < 4; ++j) gacc[mi][j] = (f32x4){0.f, 0.f, 0.f, 0.f};

    uint4 pb[4];
#pragma unroll
    for (int r = 0; r < 4; ++r) {
        int ci = tid + r * 512, n = ci >> 3, s = ci & 7;
        pb[r] = *(const uint4*)(W2aT + (size_t)n * 256 + s * 8);
    }
    for (int kt = 0; kt < 4; ++kt) {
        __syncthreads();   // Fp writes visible (kt=0); Bs safe to overwrite
#pragma unroll
        for (int r = 0; r < 4; ++r) {
            int ci = tid + r * 512, n = ci >> 3, s = ci & 7;
            ((uint4*)Bs)[n * 8 + (s ^ (n & 7))] = pb[r];
        }
        if (kt < 3) {
#pragma unroll
            for (int r = 0; r < 4; ++r) {
                int ci = tid + r * 512, n = ci >> 3, s = ci & 7;
                pb[r] = *(const uint4*)(W2aT + (size_t)n * 256 + (kt + 1) * 64 + s * 8);
            }
        }
        __syncthreads();
#pragma unroll
        for (int ks = 0; ks < 2; ++ks) {
            bf16x8 af[2], bf[4];
#pragma unroll
            for (int mi = 0; mi < 2; ++mi) {
                int r = wr * 32 + mi * 16 + m;
                int cs = kt * 8 + ks * 4 + g;
                af[mi] = *(const bf16x8*)(Fp + r * 256 + ((cs ^ (r & 7)) * 8));
            }
#pragma unroll
            for (int j = 0; j < 4; ++j) {
                int n = wc * 64 + j * 16 + m;
                bf[j] = *(const bf16x8*)(Bs + n * 64 + (((ks * 4 + g) ^ (n & 7)) * 8));
            }
#pragma unroll
            for (int mi = 0; mi < 2; ++mi)
#pragma unroll
                for (int j = 0; j < 4; ++j)
                    gacc[mi][j] = __builtin_amdgcn_mfma_f32_16x16x32_bf16(
                        af[mi], bf[j], gacc[mi][j], 0, 0, 0);
        }
    }
#pragma unroll
    for (int mi = 0; mi < 2; ++mi)
#pragma unroll
        for (int j = 0; j < 4; ++j) {
            int col = wc * 64 + j * 16 + m;
#pragma unroll
            for (int rr = 0; rr < 4; ++rr) {
                int r = wr * 32 + mi * 16 + g * 4 + rr;
                Gout[(size_t)(base + r) * 256 + col] = f2b(gacc[mi][j][rr]);
            }
        }
}

// ---- final sum over atoms (deterministic) --------------------------------

__global__ __launch_bounds__(256) void sum_bf16(const u16* __restrict__ F,
                                                float* __restrict__ out) {
    __shared__ float red[4][256];
    int b = blockIdx.x, tid = threadIdx.x;
    int cg = tid & 63, rg = tid >> 6;
    float s0 = 0, s1 = 0, s2 = 0, s3 = 0;
    const u16* Fb = F + (size_t)(b * NN + rg * 128) * 256 + cg * 4;
    for (int n = 0; n < 128; ++n) {
        ushort4 v = *(const ushort4*)(Fb + (size_t)n * 256);
        s0 += b2f(v.x); s1 += b2f(v.y); s2 += b2f(v.z); s3 += b2f(v.w);
    }
    red[rg][cg * 4 + 0] = s0; red[rg][cg * 4 + 1] = s1;
    red[rg][cg * 4 + 2] = s2; red[rg][cg * 4 + 3] = s3;
    __syncthreads();
    if (rg == 0) {
#pragma unroll
        for (int j = 0; j < 4; ++j) {
            int cc = cg * 4 + j;
            out[b * 256 + cc] = (red[0][cc] + red[1][cc]) + (red[2][cc] + red[3][cc]);
        }
    }
}

extern "C" void kernel_launch(void* const* d_in, const int* in_sizes, int n_in,
                              void* d_out, int out_size, void* d_ws, size_t ws_size,
                              hipStream_t stream) {
    const float* input_bond    = (const float*)d_in[1];
    const int*   atom_graph    = (const int*)d_in[2];
    const int*   bond_graph    = (const int*)d_in[3];
    const int*   num_nbs       = (const int*)d_in[4];
    const float* atom_features = (const float*)d_in[5];
    const float* W2 = (const float*)d_in[6];
    const float* b2 = (const float*)d_in[7];
    const float* W1 = (const float*)d_in[8];
    const float* b1 = (const float*)d_in[9];
    float* out = (float*)d_out;

    char* w = (char*)d_ws;
    u16* f0   = (u16*)w;                                      // 16MB
    u16* f1   = (u16*)(w + ((size_t)16 << 20));               // 16MB
    u16* G    = (u16*)(w + ((size_t)32 << 20));               // 16MB
    u16* Hb2  = (u16*)(w + ((size_t)48 << 20));               // 16MB
    u16* Nsg  = (u16*)(w + ((size_t)64 << 20));               // 16MB
    u16* W2aT = (u16*)(w + ((size_t)80 << 20));               // 128KB
    u16* W1T  = (u16*)(w + ((size_t)80 << 20) + (256 << 10)); // 256KB
    int* pk   = (int*)(w + ((size_t)81 << 20));               // 1.25MB

    castk<<<ROWS * HH / 1024, 256, 0, stream>>>(atom_features, f0);
    twk<<<256, 256, 0, stream>>>(W2, W2aT, 256);
    twk<<<512, 256, 0, stream>>>(W1, W1T, 512);
    hb2_kernel<<<ROWS / 8, 256, 0, stream>>>(input_bond, W2, b2, Hb2);
    pkk<<<ROWS * MAXNB / 256, 256, 0, stream>>>(atom_graph, bond_graph, num_nbs, pk);

    // G0 = F0 @ W2a  (mega skip-mode)
    mega2<<<ROWS / BM, 512, 0, stream>>>(f0, nullptr, nullptr, nullptr, W2aT,
                                         nullptr, G);

    const u16* fin = f0;
    u16* fout = f1;
    for (int d = 0; d < 3; ++d) {
        gather_k<<<ROWS / GROWS, 256, 0, stream>>>(G, Hb2, pk, Nsg);
        mega2<<<ROWS / BM, 512, 0, stream>>>(fin, Nsg, W1T, b1, W2aT,
                                             fout, (d < 2) ? G : (u16*)nullptr);
        fin = fout;
        fout = (fout == f1) ? f0 : f1;
    }
    sum_bf16<<<BB, 256, 0, stream>>>(fin, out);
}

// Round 7
// 225.130 us; speedup vs baseline: 1.8153x; 1.3422x over previous
//
#include <hip/hip_runtime.h>

// WL_DiffNet bf16-MFMA, round 7: drain-free mega GEMM.
//   A ([F|N], 64KB) staged ONCE per block via global_load_lds (pre-swizzled
//   per-lane source, linear LDS dest). K-loop streams only B (W1T/W2aT,
//   L2-hot) into double-buffered LDS tiles via global_load_lds; ONE
//   __syncthreads per kt (its vmcnt drain hits 4 L2-hot loads issued ~400cy
//   earlier => ~0 exposed). C-stores coalesced via LDS bounce (uint4/lane).
//   Phase-1: F' = relu([F|N]@W1+b1) -> LDS(AF) -> global (coalesced)
//   Phase-2: G' = F'@W2a -> LDS(Bs0) -> global   [skipped last depth]
//   Skip-mode (W1T==null): stage AF from F, phase-2 only (computes G0).

#define BB 64
#define NN 512
#define MAXNB 10
#define HH 256
#define ROWS (BB*NN)   // 32768
#define BM 64          // mega rows per block
#define GROWS 16       // gather rows per block

typedef __attribute__((ext_vector_type(8))) short bf16x8;
typedef __attribute__((ext_vector_type(4))) float f32x4;
typedef unsigned short u16;
typedef unsigned int u32;
typedef __attribute__((address_space(3))) u32 lds_u32;
typedef __attribute__((address_space(1))) const u32 glb_u32;

__device__ __forceinline__ u16 f2b(float f) {   // rne f32->bf16
    union { float f; u32 u; } v; v.f = f;
    u32 r = v.u + 0x7FFF + ((v.u >> 16) & 1);
    return (u16)(r >> 16);
}
__device__ __forceinline__ float b2f(u32 u) {   // low 16 bits -> f32
    union { u32 u; float f; } v; v.u = u << 16; return v.f;
}
__device__ __forceinline__ float b2fh(u32 u) {  // high 16 bits -> f32
    union { u32 u; float f; } v; v.u = u & 0xffff0000u; return v.f;
}
// async 16B global->LDS; lds dest must be wave-uniform (lane*16 auto-offset)
__device__ __forceinline__ void gl16(const u16* g, u16* l) {
    __builtin_amdgcn_global_load_lds((glb_u32*)g, (lds_u32*)l, 16, 0, 0);
}

// XCD-bijective swizzle (nwg % 8 == 0): XCD x owns contiguous tile chunk.
__device__ __forceinline__ int xcd_swz(int bid, int nwg) {
    return (bid & 7) * (nwg >> 3) + (bid >> 3);
}

// ---- one-time prep -------------------------------------------------------

__global__ __launch_bounds__(256) void castk(const float* __restrict__ in,
                                             u16* __restrict__ out) {
    int i = blockIdx.x * 256 + threadIdx.x;
    float4 v = ((const float4*)in)[i];
    u32 a = f2b(v.x) | ((u32)f2b(v.y) << 16);
    u32 b = f2b(v.z) | ((u32)f2b(v.w) << 16);
    ((uint2*)out)[i] = make_uint2(a, b);
}

__global__ __launch_bounds__(256) void twk(const float* __restrict__ W,
                                           u16* __restrict__ WT, int K) {
    int k = blockIdx.x, n = threadIdx.x;
    WT[(size_t)n * K + k] = f2b(W[(size_t)k * HH + n]);
}

__global__ __launch_bounds__(256) void hb2_kernel(const float* __restrict__ bond,
                                                  const float* __restrict__ W2,
                                                  const float* __restrict__ b2,
                                                  u16* __restrict__ Hb2) {
    int c = threadIdx.x;
    int r0 = blockIdx.x * 8;
    float w[5];
#pragma unroll
    for (int f = 0; f < 5; ++f) w[f] = W2[(size_t)(HH + f) * HH + c];
    float bb = b2[c];
    for (int r = r0; r < r0 + 8; ++r) {
        float s = bb;
#pragma unroll
        for (int f = 0; f < 5; ++f) s += bond[r * 5 + f] * w[f];
        Hb2[(size_t)r * HH + c] = f2b(s);
    }
}

// pk[t] = an | bn<<9 | valid<<18  (loop-invariant, computed once)
__global__ __launch_bounds__(256) void pkk(const int* __restrict__ agr,
                                           const int* __restrict__ bgr,
                                           const int* __restrict__ nnb,
                                           int* __restrict__ pk) {
    int t = blockIdx.x * 256 + threadIdx.x;   // < 327680
    int r = t / 10, k = t - r * 10;
    int an = agr[t * 2 + 1];
    int bn = bgr[t * 2 + 1];
    int valid = (k < nnb[r]) ? 1 : 0;
    pk[t] = an | (bn << 9) | (valid << 18);
}

// ---- gather: Nsg[r] = sum_k relu(G[an]+Hb2[bn]) --------------------------

__global__ __launch_bounds__(256) void gather_k(const u16* __restrict__ G,
                                                const u16* __restrict__ Hb2,
                                                const int* __restrict__ pk,
                                                u16* __restrict__ Nsg) {
    int tid = threadIdx.x;
    int base = xcd_swz(blockIdx.x, gridDim.x) * GROWS;
    int brow = base & ~511;        // batch row base (16 | 512)
    int q = tid >> 6;              // rows [q*4, q*4+4)
    int lane = tid & 63;           // uint2 slot = 4 bf16 cols
    const uint2* Gb = (const uint2*)(G + (size_t)brow * 256) + lane;
    const uint2* Hb = (const uint2*)(Hb2 + (size_t)brow * 256) + lane;
    const int* pkb = pk + (size_t)base * 10;

    for (int r = q * 4; r < q * 4 + 4; ++r) {
        float s0 = 0.f, s1 = 0.f, s2 = 0.f, s3 = 0.f;
#pragma unroll
        for (int k = 0; k < MAXNB; ++k) {
            int p = pkb[r * 10 + k];
            uint2 ga = Gb[(size_t)(p & 511) * 64];
            uint2 hb = Hb[(size_t)((p >> 9) & 511) * 64];
            float v0 = fmaxf(b2f(ga.x) + b2f(hb.x), 0.f);
            float v1 = fmaxf(b2fh(ga.x) + b2fh(hb.x), 0.f);
            float v2 = fmaxf(b2f(ga.y) + b2f(hb.y), 0.f);
            float v3 = fmaxf(b2fh(ga.y) + b2fh(hb.y), 0.f);
            bool valid = (p & (1 << 18)) != 0;
            s0 += valid ? v0 : 0.f;
            s1 += valid ? v1 : 0.f;
            s2 += valid ? v2 : 0.f;
            s3 += valid ? v3 : 0.f;
        }
        u32 lo = f2b(s0) | ((u32)f2b(s1) << 16);
        u32 hi = f2b(s2) | ((u32)f2b(s3) << 16);
        ((uint2*)(Nsg + (size_t)(base + r) * 256))[lane] = make_uint2(lo, hi);
    }
}

// ---- mega3: drain-free fused GEMM ----------------------------------------
// 512 thr, 8 waves (2 row x 4 col). LDS 128KB: AF 32 + AN 32 + Bs dbuf 64.
// All tiles XOR-swizzled on 16B slots: phys = log ^ (row&7).

__global__ __launch_bounds__(512) void mega3(const u16* __restrict__ Fbf,
                                             const u16* __restrict__ Nsg,
                                             const u16* __restrict__ W1T,
                                             const float* __restrict__ b1,
                                             const u16* __restrict__ W2aT,
                                             u16* __restrict__ Fout,
                                             u16* __restrict__ Gout) {
    __shared__ u16 AF[BM * 256];        // 32KB  (F tile; later F' tile)
    __shared__ u16 AN[BM * 256];        // 32KB  (N tile)
    __shared__ u16 Bsd[2][256 * 64];    // 64KB  (B k-tile double buffer)

    int tid = threadIdx.x;
    int base = xcd_swz(blockIdx.x, gridDim.x) * BM;
    int lane = tid & 63, wid = tid >> 6;
    int wr = wid >> 2, wc = wid & 3;
    int m = lane & 15, g = lane >> 4;

    // stage 64x256 A-region (rows of 512B, 32 slots); 4KB per wave, 4 issues
    auto stageA = [&](u16* dst, const u16* src) {
#pragma unroll
        for (int q = 0; q < 4; ++q) {
            int r = wid * 8 + q * 2 + (lane >> 5);
            int sl = (lane & 31) ^ (r & 7);
            gl16(src + (size_t)r * 256 + sl * 8, dst + wid * 2048 + q * 512);
        }
    };
    // stage 256x64 B k-tile (rows of 128B, 8 slots) from W[n][K], cols kt*64..
    auto stageB = [&](u16* dst, const u16* srcW, int kt, int Kw) {
#pragma unroll
        for (int q = 0; q < 4; ++q) {
            int n = wid * 32 + q * 8 + (lane >> 3);
            int sl = (lane & 7) ^ (n & 7);
            gl16(srcW + (size_t)n * Kw + kt * 64 + sl * 8, dst + wid * 2048 + q * 512);
        }
    };

    if (W1T) {
        stageA(AF, Fbf + (size_t)base * 256);
        stageA(AN, Nsg + (size_t)base * 256);
        stageB(Bsd[0], W1T, 0, 512);
        __syncthreads();

        f32x4 acc[2][4];
#pragma unroll
        for (int mi = 0; mi < 2; ++mi)
#pragma unroll
            for (int j = 0; j < 4; ++j) acc[mi][j] = (f32x4){0.f, 0.f, 0.f, 0.f};

        // phase-1: K=512, 8 k-tiles; A = AF (kt<4) | AN (kt>=4)
        for (int kt = 0; kt < 8; ++kt) {
            int buf = kt & 1;
            if (kt < 7) stageB(Bsd[buf ^ 1], W1T, kt + 1, 512);
            const u16* Ar = (kt < 4) ? AF : AN;
#pragma unroll
            for (int ks = 0; ks < 2; ++ks) {
                bf16x8 af[2], bfr[4];
                int slotb = (kt & 3) * 8 + ks * 4 + g;
#pragma unroll
                for (int mi = 0; mi < 2; ++mi) {
                    int r = wr * 32 + mi * 16 + m;
                    af[mi] = *(const bf16x8*)(Ar + r * 256 + ((slotb ^ (r & 7)) * 8));
                }
#pragma unroll
                for (int j = 0; j < 4; ++j) {
                    int n = wc * 64 + j * 16 + m;
                    int sb = ks * 4 + g;
                    bfr[j] = *(const bf16x8*)(Bsd[buf] + n * 64 + ((sb ^ (n & 7)) * 8));
                }
#pragma unroll
                for (int mi = 0; mi < 2; ++mi)
#pragma unroll
                    for (int j = 0; j < 4; ++j)
                        acc[mi][j] = __builtin_amdgcn_mfma_f32_16x16x32_bf16(
                            af[mi], bfr[j], acc[mi][j], 0, 0, 0);
            }
            __syncthreads();   // drains 4 L2-hot loads issued ~400cy ago
        }

        // epilogue: F' = relu(acc+b1) -> AF (swizzled); prefetch phase-2 B
        if (Gout) stageB(Bsd[0], W2aT, 0, 256);
#pragma unroll
        for (int mi = 0; mi < 2; ++mi)
#pragma unroll
            for (int j = 0; j < 4; ++j) {
                int col = wc * 64 + j * 16 + m;
                float bb = b1[col];
#pragma unroll
                for (int rr = 0; rr < 4; ++rr) {
                    int r = wr * 32 + mi * 16 + g * 4 + rr;
                    AF[r * 256 + ((col >> 3) ^ (r & 7)) * 8 + (col & 7)] =
                        f2b(fmaxf(acc[mi][j][rr] + bb, 0.f));
                }
            }
        __syncthreads();

        // coalesced F' store from AF (16B/lane)
#pragma unroll
        for (int i = 0; i < 4; ++i) {
            int c = tid + i * 512;                 // uint4 chunk id
            int r = c >> 5, sl = c & 31;
            uint4 v = ((const uint4*)AF)[r * 32 + (sl ^ (r & 7))];
            ((uint4*)(Fout + (size_t)(base + r) * 256))[sl] = v;
        }
    } else {
        // skip-mode: AF <- F directly; compute G0 = F @ W2a
        stageA(AF, Fbf + (size_t)base * 256);
        stageB(Bsd[0], W2aT, 0, 256);
        __syncthreads();
    }

    if (!Gout) return;

    // phase-2: G' = AF(F') @ W2a, K=256, 4 k-tiles
    f32x4 gacc[2][4];
#pragma unroll
    for (int mi = 0; mi < 2; ++mi)
#pragma unroll
        for (int j = 0; j < 4; ++j) gacc[mi][j] = (f32x4){0.f, 0.f, 0.f, 0.f};

    for (int kt = 0; kt < 4; ++kt) {
        int buf = kt & 1;
        if (kt < 3) stageB(Bsd[buf ^ 1], W2aT, kt + 1, 256);
#pragma unroll
        for (int ks = 0; ks < 2; ++ks) {
            bf16x8 af[2], bfr[4];
            int slotb = kt * 8 + ks * 4 + g;
#pragma unroll
            for (int mi = 0; mi < 2; ++mi) {
                int r = wr * 32 + mi * 16 + m;
                af[mi] = *(const bf16x8*)(AF + r * 256 + ((slotb ^ (r & 7)) * 8));
            }
#pragma unroll
            for (int j = 0; j < 4; ++j) {
                int n = wc * 64 + j * 16 + m;
                int sb = ks * 4 + g;
                bfr[j] = *(const bf16x8*)(Bsd[buf] + n * 64 + ((sb ^ (n & 7)) * 8));
            }
#pragma unroll
            for (int mi = 0; mi < 2; ++mi)
#pragma unroll
                for (int j = 0; j < 4; ++j)
                    gacc[mi][j] = __builtin_amdgcn_mfma_f32_16x16x32_bf16(
                        af[mi], bfr[j], gacc[mi][j], 0, 0, 0);
        }
        __syncthreads();
    }

    // G' -> Bsd[0] bounce (swizzled), then coalesced store
#pragma unroll
    for (int mi = 0; mi < 2; ++mi)
#pragma unroll
        for (int j = 0; j < 4; ++j) {
            int col = wc * 64 + j * 16 + m;
#pragma unroll
            for (int rr = 0; rr < 4; ++rr) {
                int r = wr * 32 + mi * 16 + g * 4 + rr;
                Bsd[0][r * 256 + ((col >> 3) ^ (r & 7)) * 8 + (col & 7)] =
                    f2b(gacc[mi][j][rr]);
            }
        }
    __syncthreads();
#pragma unroll
    for (int i = 0; i < 4; ++i) {
        int c = tid + i * 512;
        int r = c >> 5, sl = c & 31;
        uint4 v = ((const uint4*)Bsd[0])[r * 32 + (sl ^ (r & 7))];
        ((uint4*)(Gout + (size_t)(base + r) * 256))[sl] = v;
    }
}

// ---- final sum over atoms (deterministic) --------------------------------

__global__ __launch_bounds__(256) void sum_bf16(const u16* __restrict__ F,
                                                float* __restrict__ out) {
    __shared__ float red[4][256];
    int b = blockIdx.x, tid = threadIdx.x;
    int cg = tid & 63, rg = tid >> 6;
    float s0 = 0, s1 = 0, s2 = 0, s3 = 0;
    const u16* Fb = F + (size_t)(b * NN + rg * 128) * 256 + cg * 4;
    for (int n = 0; n < 128; ++n) {
        ushort4 v = *(const ushort4*)(Fb + (size_t)n * 256);
        s0 += b2f(v.x); s1 += b2f(v.y); s2 += b2f(v.z); s3 += b2f(v.w);
    }
    red[rg][cg * 4 + 0] = s0; red[rg][cg * 4 + 1] = s1;
    red[rg][cg * 4 + 2] = s2; red[rg][cg * 4 + 3] = s3;
    __syncthreads();
    if (rg == 0) {
#pragma unroll
        for (int j = 0; j < 4; ++j) {
            int cc = cg * 4 + j;
            out[b * 256 + cc] = (red[0][cc] + red[1][cc]) + (red[2][cc] + red[3][cc]);
        }
    }
}

extern "C" void kernel_launch(void* const* d_in, const int* in_sizes, int n_in,
                              void* d_out, int out_size, void* d_ws, size_t ws_size,
                              hipStream_t stream) {
    const float* input_bond    = (const float*)d_in[1];
    const int*   atom_graph    = (const int*)d_in[2];
    const int*   bond_graph    = (const int*)d_in[3];
    const int*   num_nbs       = (const int*)d_in[4];
    const float* atom_features = (const float*)d_in[5];
    const float* W2 = (const float*)d_in[6];
    const float* b2 = (const float*)d_in[7];
    const float* W1 = (const float*)d_in[8];
    const float* b1 = (const float*)d_in[9];
    float* out = (float*)d_out;

    char* w = (char*)d_ws;
    u16* f0   = (u16*)w;                                      // 16MB
    u16* f1   = (u16*)(w + ((size_t)16 << 20));               // 16MB
    u16* G    = (u16*)(w + ((size_t)32 << 20));               // 16MB
    u16* Hb2  = (u16*)(w + ((size_t)48 << 20));               // 16MB
    u16* Nsg  = (u16*)(w + ((size_t)64 << 20));               // 16MB
    u16* W2aT = (u16*)(w + ((size_t)80 << 20));               // 128KB
    u16* W1T  = (u16*)(w + ((size_t)80 << 20) + (256 << 10)); // 256KB
    int* pk   = (int*)(w + ((size_t)81 << 20));               // 1.25MB

    castk<<<ROWS * HH / 1024, 256, 0, stream>>>(atom_features, f0);
    twk<<<256, 256, 0, stream>>>(W2, W2aT, 256);
    twk<<<512, 256, 0, stream>>>(W1, W1T, 512);
    hb2_kernel<<<ROWS / 8, 256, 0, stream>>>(input_bond, W2, b2, Hb2);
    pkk<<<ROWS * MAXNB / 256, 256, 0, stream>>>(atom_graph, bond_graph, num_nbs, pk);

    // G0 = F0 @ W2a  (mega skip-mode)
    mega3<<<ROWS / BM, 512, 0, stream>>>(f0, nullptr, nullptr, nullptr, W2aT,
                                         nullptr, G);

    const u16* fin = f0;
    u16* fout = f1;
    for (int d = 0; d < 3; ++d) {
        gather_k<<<ROWS / GROWS, 256, 0, stream>>>(G, Hb2, pk, Nsg);
        mega3<<<ROWS / BM, 512, 0, stream>>>(fin, Nsg, W1T, b1, W2aT,
                                             fout, (d < 2) ? G : (u16*)nullptr);
        fin = fout;
        fout = (fout == f1) ? f0 : f1;
    }
    sum_bf16<<<BB, 256, 0, stream>>>(fin, out);
}

// Round 8
// 195.971 us; speedup vs baseline: 2.0854x; 1.1488x over previous
//
#include <hip/hip_runtime.h>

// WL_DiffNet bf16-MFMA, round 8: single fused per-depth kernel (mega4).
//   - gather fused in (wave-uniform coalesced L2 reads of G/Hb2) -> N in regs
//   - A LDS region aliased over time: F (kt0-7) -> N (kt8-15) -> F' -> G'
//   - B double-buffered LDS (BK=32) via global_load_lds; barriers only drain
//     same-kt L2-hot W loads
//   - LDS 64KB + launch_bounds(512,4) -> 2 blocks/CU for cross-block overlap
//   - G ping-pong (G0/G1) to avoid read/write race across blocks

#define BB 64
#define NN 512
#define MAXNB 10
#define HH 256
#define ROWS (BB*NN)   // 32768
#define BM 64          // rows per block

typedef __attribute__((ext_vector_type(8))) short bf16x8;
typedef __attribute__((ext_vector_type(4))) float f32x4;
typedef unsigned short u16;
typedef unsigned int u32;
typedef __attribute__((address_space(3))) u32 lds_u32;
typedef __attribute__((address_space(1))) const u32 glb_u32;

__device__ __forceinline__ u16 f2b(float f) {   // rne f32->bf16
    union { float f; u32 u; } v; v.f = f;
    u32 r = v.u + 0x7FFF + ((v.u >> 16) & 1);
    return (u16)(r >> 16);
}
__device__ __forceinline__ float b2f(u32 u) {   // low 16 bits -> f32
    union { u32 u; float f; } v; v.u = u << 16; return v.f;
}
__device__ __forceinline__ float b2fh(u32 u) {  // high 16 bits -> f32
    union { u32 u; float f; } v; v.u = u & 0xffff0000u; return v.f;
}
__device__ __forceinline__ void gl16(const u16* g, u16* l) {
    __builtin_amdgcn_global_load_lds((glb_u32*)g, (lds_u32*)l, 16, 0, 0);
}
// XCD-bijective swizzle (nwg % 8 == 0)
__device__ __forceinline__ int xcd_swz(int bid, int nwg) {
    return (bid & 7) * (nwg >> 3) + (bid >> 3);
}

// ---- one-time prep -------------------------------------------------------

__global__ __launch_bounds__(256) void castk(const float* __restrict__ in,
                                             u16* __restrict__ out) {
    int i = blockIdx.x * 256 + threadIdx.x;
    float4 v = ((const float4*)in)[i];
    u32 a = f2b(v.x) | ((u32)f2b(v.y) << 16);
    u32 b = f2b(v.z) | ((u32)f2b(v.w) << 16);
    ((uint2*)out)[i] = make_uint2(a, b);
}

__global__ __launch_bounds__(256) void twk(const float* __restrict__ W,
                                           u16* __restrict__ WT, int K) {
    int k = blockIdx.x, n = threadIdx.x;
    WT[(size_t)n * K + k] = f2b(W[(size_t)k * HH + n]);
}

__global__ __launch_bounds__(256) void hb2_kernel(const float* __restrict__ bond,
                                                  const float* __restrict__ W2,
                                                  const float* __restrict__ b2,
                                                  u16* __restrict__ Hb2) {
    int c = threadIdx.x;
    int r0 = blockIdx.x * 8;
    float w[5];
#pragma unroll
    for (int f = 0; f < 5; ++f) w[f] = W2[(size_t)(HH + f) * HH + c];
    float bb = b2[c];
    for (int r = r0; r < r0 + 8; ++r) {
        float s = bb;
#pragma unroll
        for (int f = 0; f < 5; ++f) s += bond[r * 5 + f] * w[f];
        Hb2[(size_t)r * HH + c] = f2b(s);
    }
}

__global__ __launch_bounds__(256) void pkk(const int* __restrict__ agr,
                                           const int* __restrict__ bgr,
                                           const int* __restrict__ nnb,
                                           int* __restrict__ pk) {
    int t = blockIdx.x * 256 + threadIdx.x;   // < 327680
    int r = t / 10, k = t - r * 10;
    int an = agr[t * 2 + 1];
    int bn = bgr[t * 2 + 1];
    int valid = (k < nnb[r]) ? 1 : 0;
    pk[t] = an | (bn << 9) | (valid << 18);
}

// ---- mega4: fused gather + [F|N]@W1 + F'@W2a -----------------------------
// 512 thr, 8 waves (2 row x 4 col), M=64, BK=32.
// LDS 64KB: A 32KB (F -> N -> F' -> G' over time) + Bs dbuf 2x16KB.
// A swizzle: 16B slot phys = log ^ (row&7).  B swizzle: phys = log ^ ((n>>1)&3).

__global__ __launch_bounds__(512, 4) void mega4(const u16* __restrict__ Fbf,
                                                const u16* __restrict__ Gin,
                                                const u16* __restrict__ Hb2,
                                                const int* __restrict__ pk,
                                                const u16* __restrict__ W1T,
                                                const float* __restrict__ b1,
                                                const u16* __restrict__ W2aT,
                                                u16* __restrict__ Fout,
                                                u16* __restrict__ Gout) {
    __shared__ u16 A_[BM * 256];       // 32KB
    __shared__ u16 Bs[2][256 * 32];    // 32KB

    int tid = threadIdx.x;
    int base = xcd_swz(blockIdx.x, gridDim.x) * BM;
    int brow = base & ~511;            // batch row base (64 | 512)
    int lane = tid & 63, wid = tid >> 6;
    int wr = wid >> 2, wc = wid & 3;
    int m = lane & 15, g = lane >> 4;

    auto stageA = [&](const u16* src) {          // 64 rows x 512B
#pragma unroll
        for (int q = 0; q < 4; ++q) {
            int c = (wid * 4 + q) * 64 + lane;   // 16B chunk 0..2047
            int r = c >> 5, ph = c & 31;
            gl16(src + (size_t)r * 256 + (ph ^ (r & 7)) * 8,
                 A_ + (wid * 4 + q) * 512);
        }
    };
    auto stageB = [&](u16* dst, const u16* W, int kt, int Kw) {  // 256 x 64B
#pragma unroll
        for (int q = 0; q < 2; ++q) {
            int c = (wid * 2 + q) * 64 + lane;   // 16B chunk 0..1023
            int n = c >> 2, ph = c & 3;
            gl16(W + (size_t)n * Kw + kt * 32 + (ph ^ ((n >> 1) & 3)) * 8,
                 dst + (wid * 2 + q) * 512);
        }
    };

    if (W1T) {
        stageA(Fbf + (size_t)base * 256);

        // fused gather: rows wid*8..wid*8+8, lane = uint2 col-slot (4 bf16)
        uint2 nreg[8];
        {
            const uint2* Gb = (const uint2*)(Gin + (size_t)brow * 256);
            const uint2* Hb = (const uint2*)(Hb2 + (size_t)brow * 256);
            const int* pkr = pk + (size_t)base * 10;
#pragma unroll
            for (int half = 0; half < 2; ++half) {
                float s[4][4];
#pragma unroll
                for (int i = 0; i < 4; ++i)
#pragma unroll
                    for (int c = 0; c < 4; ++c) s[i][c] = 0.f;
                for (int k = 0; k < MAXNB; ++k) {
#pragma unroll
                    for (int i = 0; i < 4; ++i) {
                        int r = wid * 8 + half * 4 + i;
                        int p = pkr[r * 10 + k];
                        uint2 ga = Gb[(size_t)(p & 511) * 64 + lane];
                        uint2 hb = Hb[(size_t)((p >> 9) & 511) * 64 + lane];
                        float v0 = fmaxf(b2f(ga.x) + b2f(hb.x), 0.f);
                        float v1 = fmaxf(b2fh(ga.x) + b2fh(hb.x), 0.f);
                        float v2 = fmaxf(b2f(ga.y) + b2f(hb.y), 0.f);
                        float v3 = fmaxf(b2fh(ga.y) + b2fh(hb.y), 0.f);
                        bool vl = (p & (1 << 18)) != 0;
                        s[i][0] += vl ? v0 : 0.f;
                        s[i][1] += vl ? v1 : 0.f;
                        s[i][2] += vl ? v2 : 0.f;
                        s[i][3] += vl ? v3 : 0.f;
                    }
                }
#pragma unroll
                for (int i = 0; i < 4; ++i)
                    nreg[half * 4 + i] =
                        make_uint2(f2b(s[i][0]) | ((u32)f2b(s[i][1]) << 16),
                                   f2b(s[i][2]) | ((u32)f2b(s[i][3]) << 16));
            }
        }

        stageB(Bs[0], W1T, 0, 512);
        __syncthreads();

        f32x4 acc[2][4];
#pragma unroll
        for (int mi = 0; mi < 2; ++mi)
#pragma unroll
            for (int j = 0; j < 4; ++j) acc[mi][j] = (f32x4){0.f, 0.f, 0.f, 0.f};

        // phase-1: K=512, 16 k-tiles of 32; A region: F for kt<8, N for kt>=8
        for (int kt = 0; kt < 16; ++kt) {
            int buf = kt & 1;
            if (kt < 15)       stageB(Bs[buf ^ 1], W1T, kt + 1, 512);
            else if (Gout)     stageB(Bs[buf ^ 1], W2aT, 0, 256);
            bf16x8 af[2], bfr[4];
            int asl = (kt & 7) * 4 + g;
#pragma unroll
            for (int mi = 0; mi < 2; ++mi) {
                int r = wr * 32 + mi * 16 + m;
                af[mi] = *(const bf16x8*)(A_ + r * 256 + ((asl ^ (r & 7)) * 8));
            }
#pragma unroll
            for (int j = 0; j < 4; ++j) {
                int n = wc * 64 + j * 16 + m;
                bfr[j] = *(const bf16x8*)(Bs[buf] + n * 32 + ((g ^ ((n >> 1) & 3)) * 8));
            }
#pragma unroll
            for (int mi = 0; mi < 2; ++mi)
#pragma unroll
                for (int j = 0; j < 4; ++j)
                    acc[mi][j] = __builtin_amdgcn_mfma_f32_16x16x32_bf16(
                        af[mi], bfr[j], acc[mi][j], 0, 0, 0);
            __syncthreads();
            if (kt == 7) {     // overwrite A (F dead) with gathered N
#pragma unroll
                for (int i = 0; i < 8; ++i) {
                    int r = wid * 8 + i;
                    int s16 = (lane >> 1) ^ (r & 7);
                    *(uint2*)(A_ + r * 256 + s16 * 8 + (lane & 1) * 4) = nreg[i];
                }
                __syncthreads();
            }
        }

        // epilogue: F' = relu(acc+b1) -> A (N dead)
#pragma unroll
        for (int mi = 0; mi < 2; ++mi)
#pragma unroll
            for (int j = 0; j < 4; ++j) {
                int col = wc * 64 + j * 16 + m;
                float bb = b1[col];
#pragma unroll
                for (int rr = 0; rr < 4; ++rr) {
                    int r = wr * 32 + mi * 16 + g * 4 + rr;
                    A_[r * 256 + ((col >> 3) ^ (r & 7)) * 8 + (col & 7)] =
                        f2b(fmaxf(acc[mi][j][rr] + bb, 0.f));
                }
            }
        __syncthreads();

        // coalesced F' store
#pragma unroll
        for (int i = 0; i < 4; ++i) {
            int c = tid + i * 512;
            int r = c >> 5, ph = c & 31;
            uint4 v = ((const uint4*)A_)[r * 32 + ph];
            ((uint4*)(Fout + (size_t)(base + r) * 256))[ph ^ (r & 7)] = v;
        }
    } else {
        // skip-mode: A <- F directly; compute G0 = F @ W2a
        stageA(Fbf + (size_t)base * 256);
        stageB(Bs[0], W2aT, 0, 256);
        __syncthreads();
    }

    if (!Gout) return;

    // phase-2: G' = A(F') @ W2a, K=256, 8 k-tiles of 32
    f32x4 gacc[2][4];
#pragma unroll
    for (int mi = 0; mi < 2; ++mi)
#pragma unroll
        for (int j = 0; j < 4; ++j) gacc[mi][j] = (f32x4){0.f, 0.f, 0.f, 0.f};

    for (int kt = 0; kt < 8; ++kt) {
        int buf = kt & 1;
        if (kt < 7) stageB(Bs[buf ^ 1], W2aT, kt + 1, 256);
        bf16x8 af[2], bfr[4];
        int asl = kt * 4 + g;
#pragma unroll
        for (int mi = 0; mi < 2; ++mi) {
            int r = wr * 32 + mi * 16 + m;
            af[mi] = *(const bf16x8*)(A_ + r * 256 + ((asl ^ (r & 7)) * 8));
        }
#pragma unroll
        for (int j = 0; j < 4; ++j) {
            int n = wc * 64 + j * 16 + m;
            bfr[j] = *(const bf16x8*)(Bs[buf] + n * 32 + ((g ^ ((n >> 1) & 3)) * 8));
        }
#pragma unroll
        for (int mi = 0; mi < 2; ++mi)
#pragma unroll
            for (int j = 0; j < 4; ++j)
                gacc[mi][j] = __builtin_amdgcn_mfma_f32_16x16x32_bf16(
                    af[mi], bfr[j], gacc[mi][j], 0, 0, 0);
        __syncthreads();
    }

    // G' -> A (F' reads done), then coalesced store
#pragma unroll
    for (int mi = 0; mi < 2; ++mi)
#pragma unroll
        for (int j = 0; j < 4; ++j) {
            int col = wc * 64 + j * 16 + m;
#pragma unroll
            for (int rr = 0; rr < 4; ++rr) {
                int r = wr * 32 + mi * 16 + g * 4 + rr;
                A_[r * 256 + ((col >> 3) ^ (r & 7)) * 8 + (col & 7)] =
                    f2b(gacc[mi][j][rr]);
            }
        }
    __syncthreads();
#pragma unroll
    for (int i = 0; i < 4; ++i) {
        int c = tid + i * 512;
        int r = c >> 5, ph = c & 31;
        uint4 v = ((const uint4*)A_)[r * 32 + ph];
        ((uint4*)(Gout + (size_t)(base + r) * 256))[ph ^ (r & 7)] = v;
    }
}

// ---- final sum over atoms (deterministic) --------------------------------

__global__ __launch_bounds__(256) void sum_bf16(const u16* __restrict__ F,
                                                float* __restrict__ out) {
    __shared__ float red[4][256];
    int b = blockIdx.x, tid = threadIdx.x;
    int cg = tid & 63, rg = tid >> 6;
    float s0 = 0, s1 = 0, s2 = 0, s3 = 0;
    const u16* Fb = F + (size_t)(b * NN + rg * 128) * 256 + cg * 4;
    for (int n = 0; n < 128; ++n) {
        ushort4 v = *(const ushort4*)(Fb + (size_t)n * 256);
        s0 += b2f(v.x); s1 += b2f(v.y); s2 += b2f(v.z); s3 += b2f(v.w);
    }
    red[rg][cg * 4 + 0] = s0; red[rg][cg * 4 + 1] = s1;
    red[rg][cg * 4 + 2] = s2; red[rg][cg * 4 + 3] = s3;
    __syncthreads();
    if (rg == 0) {
#pragma unroll
        for (int j = 0; j < 4; ++j) {
            int cc = cg * 4 + j;
            out[b * 256 + cc] = (red[0][cc] + red[1][cc]) + (red[2][cc] + red[3][cc]);
        }
    }
}

extern "C" void kernel_launch(void* const* d_in, const int* in_sizes, int n_in,
                              void* d_out, int out_size, void* d_ws, size_t ws_size,
                              hipStream_t stream) {
    const float* input_bond    = (const float*)d_in[1];
    const int*   atom_graph    = (const int*)d_in[2];
    const int*   bond_graph    = (const int*)d_in[3];
    const int*   num_nbs       = (const int*)d_in[4];
    const float* atom_features = (const float*)d_in[5];
    const float* W2 = (const float*)d_in[6];
    const float* b2 = (const float*)d_in[7];
    const float* W1 = (const float*)d_in[8];
    const float* b1 = (const float*)d_in[9];
    float* out = (float*)d_out;

    char* w = (char*)d_ws;
    u16* f0   = (u16*)w;                                      // 16MB
    u16* f1   = (u16*)(w + ((size_t)16 << 20));               // 16MB
    u16* G0   = (u16*)(w + ((size_t)32 << 20));               // 16MB
    u16* G1   = (u16*)(w + ((size_t)48 << 20));               // 16MB
    u16* Hb2  = (u16*)(w + ((size_t)64 << 20));               // 16MB
    u16* W2aT = (u16*)(w + ((size_t)80 << 20));               // 128KB
    u16* W1T  = (u16*)(w + ((size_t)80 << 20) + (256 << 10)); // 256KB
    int* pk   = (int*)(w + ((size_t)81 << 20));               // 1.25MB

    castk<<<ROWS * HH / 1024, 256, 0, stream>>>(atom_features, f0);
    twk<<<256, 256, 0, stream>>>(W2, W2aT, 256);
    twk<<<512, 256, 0, stream>>>(W1, W1T, 512);
    hb2_kernel<<<ROWS / 8, 256, 0, stream>>>(input_bond, W2, b2, Hb2);
    pkk<<<ROWS * MAXNB / 256, 256, 0, stream>>>(atom_graph, bond_graph, num_nbs, pk);

    // G0 = F0 @ W2a  (skip-mode)
    mega4<<<ROWS / BM, 512, 0, stream>>>(f0, nullptr, nullptr, nullptr,
                                         nullptr, nullptr, W2aT, nullptr, G0);
    // depth 0..2 (G ping-pong; last depth skips phase-2)
    mega4<<<ROWS / BM, 512, 0, stream>>>(f0, G0, Hb2, pk, W1T, b1, W2aT, f1, G1);
    mega4<<<ROWS / BM, 512, 0, stream>>>(f1, G1, Hb2, pk, W1T, b1, W2aT, f0, G0);
    mega4<<<ROWS / BM, 512, 0, stream>>>(f0, G0, Hb2, pk, W1T, b1, W2aT, f1, nullptr);

    sum_bf16<<<BB, 256, 0, stream>>>(f1, out);
}

// Round 9
// 159.989 us; speedup vs baseline: 2.5544x; 1.2249x over previous
//
#include <hip/hip_runtime.h>

// WL_DiffNet bf16-MFMA, round 9: barrier-free k-loop (mega5).
//   - B never in LDS: W1/W2a pre-packed fragment-major (Wp[kt][nq][lane],
//     16B/lane) -> coalesced 1KB direct L2 loads, register-prefetched 1 kt
//     ahead. Zero barriers inside the k-loop (4 per block total).
//   - wave tile 64x32 (8 col-groups) -> no B duplication across waves.
//   - A(F) + N in LDS (64KB, 2 blocks/CU); A region: F -> F'.
//   - gather: zero-row trick (invalid -> row 32768 of G/Hb2, zeroed in prep;
//     pk packs two absolute 16-bit row ids) -> no valid-mask selects.
// Math bit-identical to rounds 3-8 (absmax must stay 0.0625).

#define BB 64
#define NN 512
#define MAXNB 10
#define HH 256
#define ROWS (BB*NN)   // 32768
#define BM 64          // rows per block
#define ZROW 32768     // zero row index in G/Hb2 buffers

typedef __attribute__((ext_vector_type(8))) short bf16x8;
typedef __attribute__((ext_vector_type(4))) float f32x4;
typedef unsigned short u16;
typedef unsigned int u32;
typedef __attribute__((address_space(3))) u32 lds_u32;
typedef __attribute__((address_space(1))) const u32 glb_u32;

__device__ __forceinline__ u16 f2b(float f) {   // rne f32->bf16
    union { float f; u32 u; } v; v.f = f;
    u32 r = v.u + 0x7FFF + ((v.u >> 16) & 1);
    return (u16)(r >> 16);
}
__device__ __forceinline__ float b2f(u32 u) {   // low 16 bits -> f32
    union { u32 u; float f; } v; v.u = u << 16; return v.f;
}
__device__ __forceinline__ float b2fh(u32 u) {  // high 16 bits -> f32
    union { u32 u; float f; } v; v.u = u & 0xffff0000u; return v.f;
}
__device__ __forceinline__ void gl16(const u16* g, u16* l) {
    __builtin_amdgcn_global_load_lds((glb_u32*)g, (lds_u32*)l, 16, 0, 0);
}
// XCD-bijective swizzle (nwg % 8 == 0)
__device__ __forceinline__ int xcd_swz(int bid, int nwg) {
    return (bid & 7) * (nwg >> 3) + (bid >> 3);
}

// ---- one-time prep -------------------------------------------------------

__global__ __launch_bounds__(256) void castk(const float* __restrict__ in,
                                             u16* __restrict__ out) {
    int i = blockIdx.x * 256 + threadIdx.x;
    float4 v = ((const float4*)in)[i];
    u32 a = f2b(v.x) | ((u32)f2b(v.y) << 16);
    u32 b = f2b(v.z) | ((u32)f2b(v.w) << 16);
    ((uint2*)out)[i] = make_uint2(a, b);
}

__global__ __launch_bounds__(256) void hb2_kernel(const float* __restrict__ bond,
                                                  const float* __restrict__ W2,
                                                  const float* __restrict__ b2,
                                                  u16* __restrict__ Hb2) {
    int c = threadIdx.x;
    int r0 = blockIdx.x * 8;
    float w[5];
#pragma unroll
    for (int f = 0; f < 5; ++f) w[f] = W2[(size_t)(HH + f) * HH + c];
    float bb = b2[c];
    for (int r = r0; r < r0 + 8; ++r) {
        float s = bb;
#pragma unroll
        for (int f = 0; f < 5; ++f) s += bond[r * 5 + f] * w[f];
        Hb2[(size_t)r * HH + c] = f2b(s);
    }
}

// pk[t] = absrowA | absrowB<<16; invalid -> ZROW (zeroed row)
__global__ __launch_bounds__(256) void pkk(const int* __restrict__ agr,
                                           const int* __restrict__ bgr,
                                           const int* __restrict__ nnb,
                                           u32* __restrict__ pk) {
    int t = blockIdx.x * 256 + threadIdx.x;   // < 327680
    int r = t / 10, k = t - r * 10;
    int brow = (r >> 9) << 9;
    bool valid = (k < nnb[r]);
    u32 pA = valid ? (u32)(brow + agr[t * 2 + 1]) : (u32)ZROW;
    u32 pB = valid ? (u32)(brow + bgr[t * 2 + 1]) : (u32)ZROW;
    pk[t] = pA | (pB << 16);
}

// fragment-major weight pack: Wp[((kt*16+nq)*64+lane)*8 + e] =
//   bf16(W[(kt*32 + (lane>>4)*8 + e) * 256 + nq*16 + (lane&15)])
__global__ __launch_bounds__(256) void wpk(const float* __restrict__ W,
                                           u16* __restrict__ Wp) {
    int o = blockIdx.x * 256 + threadIdx.x;
    int e = o & 7, lane = (o >> 3) & 63, nq = (o >> 9) & 15, kt = o >> 13;
    int k = kt * 32 + (lane >> 4) * 8 + e;
    int n = nq * 16 + (lane & 15);
    Wp[o] = f2b(W[(size_t)k * HH + n]);
}

// zero row ZROW of G0/G1/Hb2
__global__ __launch_bounds__(256) void zrow(u16* G0, u16* G1, u16* Hb2) {
    int t = threadIdx.x;
    G0[(size_t)ZROW * 256 + t] = 0;
    G1[(size_t)ZROW * 256 + t] = 0;
    Hb2[(size_t)ZROW * 256 + t] = 0;
}

// ---- mega5: fused gather + [F|N]@W1 + F'@W2a, barrier-free k-loop --------
// 512 thr, 8 waves; wave wc owns cols wc*32..wc*32+32, all 64 rows.
// LDS 64KB: A_ (F -> F') + N_ (N -> G'). B direct from packed W, reg-prefetch.

__global__ __launch_bounds__(512, 4) void mega5(const u16* __restrict__ Fbf,
                                                const u16* __restrict__ Gall,
                                                const u16* __restrict__ Hall,
                                                const u32* __restrict__ pk,
                                                const u16* __restrict__ Wp1,
                                                const float* __restrict__ b1,
                                                const u16* __restrict__ Wp2,
                                                u16* __restrict__ Fout,
                                                u16* __restrict__ Gout) {
    __shared__ u16 A_[BM * 256];   // 32KB
    __shared__ u16 N_[BM * 256];   // 32KB

    int tid = threadIdx.x;
    int base = xcd_swz(blockIdx.x, gridDim.x) * BM;
    int lane = tid & 63, wid = tid >> 6;
    int wc = wid;                  // col group
    int m = lane & 15, g = lane >> 4;

    // stage F -> A_ (async, swizzled source / linear dest)
#pragma unroll
    for (int q = 0; q < 4; ++q) {
        int c = (wid * 4 + q) * 64 + lane;
        int r = c >> 5, ph = c & 31;
        gl16(Fbf + (size_t)(base + r) * 256 + (ph ^ (r & 7)) * 8,
             A_ + (wid * 4 + q) * 512);
    }

    uint4 breg[2];

    if (Wp1) {
        // fused gather: wave rows wid*8..+8; lane = uint2 col-slot
        const uint2* Gb = (const uint2*)Gall;
        const uint2* Hb = (const uint2*)Hall;
        const u32* pkr = pk + (size_t)base * 10;
#pragma unroll
        for (int i = 0; i < 8; ++i) {
            int r = wid * 8 + i;
            float s0 = 0.f, s1 = 0.f, s2 = 0.f, s3 = 0.f;
#pragma unroll
            for (int k = 0; k < MAXNB; ++k) {
                u32 p = pkr[r * 10 + k];
                uint2 ga = Gb[(size_t)(p & 0xffffu) * 64 + lane];
                uint2 hb = Hb[(size_t)(p >> 16) * 64 + lane];
                s0 += fmaxf(b2f(ga.x) + b2f(hb.x), 0.f);
                s1 += fmaxf(b2fh(ga.x) + b2fh(hb.x), 0.f);
                s2 += fmaxf(b2f(ga.y) + b2f(hb.y), 0.f);
                s3 += fmaxf(b2fh(ga.y) + b2fh(hb.y), 0.f);
            }
            u32 lo = f2b(s0) | ((u32)f2b(s1) << 16);
            u32 hi = f2b(s2) | ((u32)f2b(s3) << 16);
            int s16 = (lane >> 1) ^ (r & 7);
            *(uint2*)(N_ + r * 256 + s16 * 8 + (lane & 1) * 4) = make_uint2(lo, hi);
        }

        // prefetch B kt0
#pragma unroll
        for (int j = 0; j < 2; ++j)
            breg[j] = *(const uint4*)(Wp1 + ((size_t)(wc * 2 + j) * 64 + lane) * 8);
        __syncthreads();   // B1: stageA (all waves) + N_ writes visible

        f32x4 acc[4][2];
#pragma unroll
        for (int mi = 0; mi < 4; ++mi)
#pragma unroll
            for (int j = 0; j < 2; ++j) acc[mi][j] = (f32x4){0.f, 0.f, 0.f, 0.f};

        // phase-1: K=512, 16 kt, BARRIER-FREE; A from A_ (kt<8) or N_ (kt>=8)
        for (int kt = 0; kt < 16; ++kt) {
            bf16x8 bcur[2];
            bcur[0] = *(bf16x8*)&breg[0];
            bcur[1] = *(bf16x8*)&breg[1];
            if (kt < 15) {
#pragma unroll
                for (int j = 0; j < 2; ++j)
                    breg[j] = *(const uint4*)(Wp1 +
                        ((size_t)((kt + 1) * 16 + wc * 2 + j) * 64 + lane) * 8);
            } else if (Gout) {
#pragma unroll
                for (int j = 0; j < 2; ++j)
                    breg[j] = *(const uint4*)(Wp2 +
                        ((size_t)(wc * 2 + j) * 64 + lane) * 8);
            }
            const u16* Ar = (kt < 8) ? A_ : N_;
            int asl = (kt & 7) * 4 + g;
            bf16x8 af[4];
#pragma unroll
            for (int mi = 0; mi < 4; ++mi) {
                int r = mi * 16 + m;
                af[mi] = *(const bf16x8*)(Ar + r * 256 + ((asl ^ (r & 7)) * 8));
            }
#pragma unroll
            for (int mi = 0; mi < 4; ++mi)
#pragma unroll
                for (int j = 0; j < 2; ++j)
                    acc[mi][j] = __builtin_amdgcn_mfma_f32_16x16x32_bf16(
                        af[mi], bcur[j], acc[mi][j], 0, 0, 0);
        }
        __syncthreads();   // B2: all waves done reading A_/N_

        // F' = relu(acc+b1) -> A_ (F dead)
#pragma unroll
        for (int mi = 0; mi < 4; ++mi)
#pragma unroll
            for (int j = 0; j < 2; ++j) {
                int col = wc * 32 + j * 16 + m;
                float bb = b1[col];
#pragma unroll
                for (int rr = 0; rr < 4; ++rr) {
                    int r = mi * 16 + g * 4 + rr;
                    A_[r * 256 + ((col >> 3) ^ (r & 7)) * 8 + (col & 7)] =
                        f2b(fmaxf(acc[mi][j][rr] + bb, 0.f));
                }
            }
        __syncthreads();   // B3: F' visible

        // coalesced F' store
#pragma unroll
        for (int i = 0; i < 4; ++i) {
            int c = tid + i * 512;
            int r = c >> 5, ph = c & 31;
            uint4 v = ((const uint4*)A_)[r * 32 + ph];
            ((uint4*)(Fout + (size_t)(base + r) * 256))[ph ^ (r & 7)] = v;
        }
    } else {
        // skip-mode: A_ <- F; prefetch Wp2 kt0
        if (Gout) {
#pragma unroll
            for (int j = 0; j < 2; ++j)
                breg[j] = *(const uint4*)(Wp2 + ((size_t)(wc * 2 + j) * 64 + lane) * 8);
        }
        __syncthreads();   // B1
    }

    if (!Gout) return;

    // phase-2: G' = A_(F') @ W2a, K=256, 8 kt, BARRIER-FREE
    f32x4 gacc[4][2];
#pragma unroll
    for (int mi = 0; mi < 4; ++mi)
#pragma unroll
        for (int j = 0; j < 2; ++j) gacc[mi][j] = (f32x4){0.f, 0.f, 0.f, 0.f};

    for (int kt = 0; kt < 8; ++kt) {
        bf16x8 bcur[2];
        bcur[0] = *(bf16x8*)&breg[0];
        bcur[1] = *(bf16x8*)&breg[1];
        if (kt < 7) {
#pragma unroll
            for (int j = 0; j < 2; ++j)
                breg[j] = *(const uint4*)(Wp2 +
                    ((size_t)((kt + 1) * 16 + wc * 2 + j) * 64 + lane) * 8);
        }
        int asl = kt * 4 + g;
        bf16x8 af[4];
#pragma unroll
        for (int mi = 0; mi < 4; ++mi) {
            int r = mi * 16 + m;
            af[mi] = *(const bf16x8*)(A_ + r * 256 + ((asl ^ (r & 7)) * 8));
        }
#pragma unroll
        for (int mi = 0; mi < 4; ++mi)
#pragma unroll
            for (int j = 0; j < 2; ++j)
                gacc[mi][j] = __builtin_amdgcn_mfma_f32_16x16x32_bf16(
                    af[mi], bcur[j], gacc[mi][j], 0, 0, 0);
    }

    // G' -> N_ bounce (N dead; no barrier needed before writes: nobody reads N_)
#pragma unroll
    for (int mi = 0; mi < 4; ++mi)
#pragma unroll
        for (int j = 0; j < 2; ++j) {
            int col = wc * 32 + j * 16 + m;
#pragma unroll
            for (int rr = 0; rr < 4; ++rr) {
                int r = mi * 16 + g * 4 + rr;
                N_[r * 256 + ((col >> 3) ^ (r & 7)) * 8 + (col & 7)] =
                    f2b(gacc[mi][j][rr]);
            }
        }
    __syncthreads();   // B4: G' visible
#pragma unroll
    for (int i = 0; i < 4; ++i) {
        int c = tid + i * 512;
        int r = c >> 5, ph = c & 31;
        uint4 v = ((const uint4*)N_)[r * 32 + ph];
        ((uint4*)(Gout + (size_t)(base + r) * 256))[ph ^ (r & 7)] = v;
    }
}

// ---- final sum over atoms (deterministic) --------------------------------

__global__ __launch_bounds__(256) void sum_bf16(const u16* __restrict__ F,
                                                float* __restrict__ out) {
    __shared__ float red[4][256];
    int b = blockIdx.x, tid = threadIdx.x;
    int cg = tid & 63, rg = tid >> 6;
    float s0 = 0, s1 = 0, s2 = 0, s3 = 0;
    const u16* Fb = F + (size_t)(b * NN + rg * 128) * 256 + cg * 4;
    for (int n = 0; n < 128; ++n) {
        ushort4 v = *(const ushort4*)(Fb + (size_t)n * 256);
        s0 += b2f(v.x); s1 += b2f(v.y); s2 += b2f(v.z); s3 += b2f(v.w);
    }
    red[rg][cg * 4 + 0] = s0; red[rg][cg * 4 + 1] = s1;
    red[rg][cg * 4 + 2] = s2; red[rg][cg * 4 + 3] = s3;
    __syncthreads();
    if (rg == 0) {
#pragma unroll
        for (int j = 0; j < 4; ++j) {
            int cc = cg * 4 + j;
            out[b * 256 + cc] = (red[0][cc] + red[1][cc]) + (red[2][cc] + red[3][cc]);
        }
    }
}

extern "C" void kernel_launch(void* const* d_in, const int* in_sizes, int n_in,
                              void* d_out, int out_size, void* d_ws, size_t ws_size,
                              hipStream_t stream) {
    const float* input_bond    = (const float*)d_in[1];
    const int*   atom_graph    = (const int*)d_in[2];
    const int*   bond_graph    = (const int*)d_in[3];
    const int*   num_nbs       = (const int*)d_in[4];
    const float* atom_features = (const float*)d_in[5];
    const float* W2 = (const float*)d_in[6];
    const float* b2 = (const float*)d_in[7];
    const float* W1 = (const float*)d_in[8];
    const float* b1 = (const float*)d_in[9];
    float* out = (float*)d_out;

    char* w = (char*)d_ws;
    u16* f0  = (u16*)w;                          // 16MB
    u16* f1  = (u16*)(w + ((size_t)16 << 20));   // 16MB
    u16* G0  = (u16*)(w + ((size_t)32 << 20));   // 16MB + zero row
    u16* G1  = (u16*)(w + ((size_t)49 << 20));   // 16MB + zero row
    u16* Hb2 = (u16*)(w + ((size_t)66 << 20));   // 16MB + zero row
    u16* Wp1 = (u16*)(w + ((size_t)83 << 20));            // 256KB
    u16* Wp2 = (u16*)(w + ((size_t)83 << 20) + (512 << 10)); // 128KB
    u32* pk  = (u32*)(w + ((size_t)84 << 20));   // 1.25MB

    castk<<<ROWS * HH / 1024, 256, 0, stream>>>(atom_features, f0);
    hb2_kernel<<<ROWS / 8, 256, 0, stream>>>(input_bond, W2, b2, Hb2);
    pkk<<<ROWS * MAXNB / 256, 256, 0, stream>>>(atom_graph, bond_graph, num_nbs, pk);
    wpk<<<512, 256, 0, stream>>>(W1, Wp1);   // 131072 elems (kt 0..15)
    wpk<<<256, 256, 0, stream>>>(W2, Wp2);   // 65536 elems (kt 0..7, W2a part)
    zrow<<<1, 256, 0, stream>>>(G0, G1, Hb2);

    // G0 = F0 @ W2a  (skip-mode)
    mega5<<<ROWS / BM, 512, 0, stream>>>(f0, nullptr, nullptr, nullptr,
                                         nullptr, nullptr, Wp2, nullptr, G0);
    // depth 0..2 (G ping-pong; last depth skips phase-2)
    mega5<<<ROWS / BM, 512, 0, stream>>>(f0, G0, Hb2, pk, Wp1, b1, Wp2, f1, G1);
    mega5<<<ROWS / BM, 512, 0, stream>>>(f1, G1, Hb2, pk, Wp1, b1, Wp2, f0, G0);
    mega5<<<ROWS / BM, 512, 0, stream>>>(f0, G0, Hb2, pk, Wp1, b1, Wp2, f1, nullptr);

    sum_bf16<<<BB, 256, 0, stream>>>(f1, out);
}